// Round 6
// baseline (400.408 us; speedup 1.0000x reference)
//
#include <hip/hip_runtime.h>

// AdEx neuron simulation: T=500 steps, N=100000 neurons. One wave per 64 neurons.
// R9: LDS-staged input, register ring abandoned.
// History: R3 130us (DEPTH12 reg ring), R7 175us (2n/thread REGRESSED),
// R8 137us (DEPTH24 NEUTRAL -> compiler caps in-flight ring ~12; VGPR only +8).
// Diagnosis: vmcnt retires IN ORDER and is shared by loads AND stores. The
// per-step consume-wait on the load ring transitively waits on nontemporal
// store retirement (HBM write path) from ~DEPTH steps back -> store latency
// sits on the per-step critical path; ring depth can't remove it.
// Fix: decouple consume from vmcnt:
//  - I staged through LDS: 32-step tiles (8KB), global_load_lds width 16
//    (8 DMA instrs/tile), double-buffered in TWO separate __shared__ arrays
//    with a 2x-unrolled tile loop (static buffer names -> clean alias info).
//  - consume = ds_read_b32 (lane reads own 4B slot; 2-way bank alias = free),
//    prefetched 4 ahead -> waits are lgkmcnt, independent of stores.
//  - one asm s_waitcnt vmcnt(32) per tile boundary: retires the stagings while
//    leaving the 32 newest stores outstanding -> store latency amortized /32.
//  - 64-thread blocks = 1 wave -> no barriers. LDS 16KB/block, 6.1 blocks/CU.
// Per-neuron math bit-identical to R3 -> absmax must stay 4.8828e-4.
// Numerics: contract(off), left-to-right order, precise expf.

#define TS 32   // timesteps per LDS tile

__device__ __forceinline__ void stage16(const void* g, void* l) {
    // DMA 16B/lane global->LDS; LDS dest = uniform base + lane*16 (m104).
    __builtin_amdgcn_global_load_lds(
        (const __attribute__((address_space(1))) void*)g,
        (__attribute__((address_space(3))) void*)l, 16, 0, 0);
}
__device__ __forceinline__ void stage4(const void* g, void* l) {
    __builtin_amdgcn_global_load_lds(
        (const __attribute__((address_space(1))) void*)g,
        (__attribute__((address_space(3))) void*)l, 4, 0, 0);
}

template <bool FULL>
__device__ __forceinline__ void run_sim(
    const float* __restrict__ I,
    const float* __restrict__ v0,
    const float* __restrict__ c0,
    const int*   __restrict__ ref0,
    float*       __restrict__ out,
    int N, int T, float* bufA, float* bufB)
{
#pragma clang fp contract(off)
    const float EL       = (float)(-70.6e-3);
    const float VT       = (float)(-50.4e-3);
    const float DELTAT   = (float)(2e-3);
    const float R_DELTAT = (float)(1.0 / (double)((float)(2e-3)));  // fl(1/d)
    const float NEG_GL   = (float)(-30e-9);
    const float GLDT     = (float)(30e-9 * 2e-3);        // GL*DELTAT
    const float DT_CM    = (float)(1e-3 / 281e-12);      // DT/CM
    const float DT_TAUW  = (float)(1e-3 / 144e-3);       // DT/TAUW
    const float Af       = (float)(4e-9);
    const float Bf       = (float)(0.0805e-9);
    const int   REF_STEPS = 2;

    const int lane   = threadIdx.x;        // 64-thread block = 1 wave
    const int n_base = blockIdx.x * 64;
    const int n      = n_base + lane;
    const bool active = FULL || (n < N);
    const int  nld    = FULL ? n : (n < N ? n : N - 1);

    float v  = v0[nld];
    float c  = c0[nld];
    int   rf = ref0[nld];

    const unsigned stride_b = (unsigned)N * 4u;
    const char* Ic = (const char*)I;
    char*       oc = (char*)out;

    // One simulation step. Same op order as R3 (bit-identical).
    auto step = [&](float It) -> float {
        bool  in_ref = rf > 0;
        float v_eff  = in_ref ? EL : v;

        float x   = v_eff - VT;
        float y0  = x * R_DELTAT;
        float e   = fmaf(-DELTAT, y0, x);
        float arg = fmaf(e, R_DELTAT, y0);
        arg = fminf(arg, 15.0f);
        float exp_term = GLDT * expf(arg);

        float acc = NEG_GL * (v_eff - EL);
        acc = acc + exp_term;
        acc = acc - c;
        acc = acc + It;
        float dv = DT_CM * acc;

        float v_new = in_ref ? EL : (v_eff + dv);
        float c_new = c + DT_TAUW * ((Af * (v_eff - EL)) - c);

        bool  spike = v_new >= VT;
        float v_out = spike ? EL : v_new;

        c  = spike ? (c_new + Bf) : c_new;
        rf = spike ? REF_STEPS : (in_ref ? rf - 1 : 0);
        v  = v_out;
        return v_out;
    };

    // 16B-staging per-lane source: lane l covers row (l>>4), col bytes
    // n_base*4 + (l&15)*16. Column part is lane-constant -> clamp once.
    int col16 = n_base * 4 + (lane & 15) * 16;
    if (!FULL) { int mx = N * 4 - 16; col16 = col16 < mx ? col16 : mx; }
    const char* gst = Ic + (size_t)(lane >> 4) * stride_b + (size_t)col16;

    int col4 = n * 4;
    if (!FULL) { int mx = N * 4 - 4; col4 = col4 < mx ? col4 : mx; }

    unsigned off = (unsigned)n * 4u;   // store byte offset, walks t

    const int nt = (T + TS - 1) / TS;

    // Stage tile k (rows k*TS .. min(k*TS+TS,T)-1) into sb. 4 rows per 16B
    // DMA instr; tail rows (<4) staged per-row with 4B DMA.
    auto stage_tile = [&](int k, float* sb) {
        int t0   = k * TS;
        int rows = T - t0; if (rows > TS) rows = TS;
        int full = rows >> 2;
        for (int i = 0; i < full; ++i) {
            stage16(gst, sb + i * 256);          // 256 floats = 1024B = 4 rows
            gst += 4 * (size_t)stride_b;
        }
        int rem = rows & 3;
        if (rem) {
            const char* g4 = Ic + (size_t)(t0 + (full << 2)) * stride_b + (size_t)col4;
            float* lb = sb + (full << 2) * 64;
            for (int r = 0; r < rem; ++r) {
                stage4(g4, lb);
                g4 += stride_b; lb += 64;
            }
        }
    };

    // One tile: stage next tile into sb, compute this tile from rb.
    auto tile_body = [&](int k, const float* rb, float* sb) {
        if (k + 1 < nt) stage_tile(k + 1, sb);

        int rows = T - k * TS; if (rows > TS) rows = TS;

        float ring[4];
#pragma unroll
        for (int i = 0; i < 4; ++i)
            if (i < rows) ring[i] = rb[i * 64 + lane];

#pragma unroll
        for (int r = 0; r < TS; ++r) {
            if (r < rows) {
                float It = ring[r & 3];
                if (r + 4 < rows) ring[r & 3] = rb[(r + 4) * 64 + lane];
                float v_out = step(It);
                if (active)
                    __builtin_nontemporal_store(v_out, (float*)(oc + off));
                off += stride_b;
            }
        }
        // Retire this body's stagings (issued before its 32 stores) while
        // leaving the 32 newest stores outstanding. In-order vmcnt: counts
        // down by retiring oldest first -> stagings drain, stores may remain.
        asm volatile("s_waitcnt vmcnt(32)" ::: "memory");
    };

    // Prologue: stage tile 0 and drain (only stagings outstanding).
    stage_tile(0, bufA);
    asm volatile("s_waitcnt vmcnt(0)" ::: "memory");

    // 2x-unrolled tile loop -> static LDS buffer names (clean aliasing).
    for (int k = 0; k < nt; k += 2) {
        tile_body(k, bufA, bufB);
        if (k + 1 < nt) tile_body(k + 1, bufB, bufA);
    }
}

__global__ __launch_bounds__(64) void adex_kernel(
    const float* __restrict__ I,
    const float* __restrict__ v0,
    const float* __restrict__ c0,
    const int*   __restrict__ ref0,
    float*       __restrict__ out,
    int N, int T)
{
    __shared__ float bufA[TS * 64];   // 8 KB
    __shared__ float bufB[TS * 64];   // 8 KB

    if (blockIdx.x * 64 + 64 <= (unsigned)N) {
        run_sim<true >(I, v0, c0, ref0, out, N, T, bufA, bufB);
    } else {
        run_sim<false>(I, v0, c0, ref0, out, N, T, bufA, bufB);
    }
}

extern "C" void kernel_launch(void* const* d_in, const int* in_sizes, int n_in,
                              void* d_out, int out_size, void* d_ws, size_t ws_size,
                              hipStream_t stream) {
    const float* I    = (const float*)d_in[0];
    const float* v0   = (const float*)d_in[1];
    const float* c0   = (const float*)d_in[2];
    const int*   ref0 = (const int*)d_in[3];
    float*       out  = (float*)d_out;

    int N = in_sizes[1];            // 100000
    int T = in_sizes[0] / N;        // 500

    dim3 block(64);
    dim3 grid((N + 63) / 64);       // 1563 one-wave blocks -> 6-7 waves/CU
    adex_kernel<<<grid, block, 0, stream>>>(I, v0, c0, ref0, out, N, T);
}

// Round 7
// 341.037 us; speedup vs baseline: 1.1741x; 1.1741x over previous
//
#include <hip/hip_runtime.h>

// AdEx neuron simulation: T=500 steps, N=100000 neurons. One thread per neuron.
// R10 = R3 with ONE change: plain stores instead of nontemporal stores.
// Store-retire theory (from R3/R7/R8/R9 counter history):
//  - vmcnt retires IN ORDER, shared by loads+stores. R3's per-step consume
//    wait on the 12-deep load ring transitively waits a ~12-step-old
//    NONTEMPORAL store; nt bypasses cache -> retires at HBM-write latency,
//    queue-inflated to ~7500 cyc. Period = 7500/12 = 624 cyc/step = R3 exact.
//  - R9 decoupled LOADS entirely (LDS staging) and got SLOWER -> loads are
//    not the binder; the 1-nt-store/step stream is.
//  - R8's DEPTH-24 null: VGPR only +8 -> compiler sank the ring, effective
//    depth stayed ~12 (codegen artifact, not HW).
// Plain stores retire on L2-accept (~300 cyc; writeback drains async via
// L2/L3) -> the in-order vmcnt chain drops the multi-us store latency.
// Risk accepted: write-allocate evicts some of I from L3 -> FETCH_SIZE may
// rise 98->~150MB; BW budget (~6.3 TB/s) easily covers it.
// Everything else bit-identical to R3 -> absmax must stay 4.8828e-4.
// Numerics: contract(off), left-to-right order, precise expf.

#define DEPTH 12

__global__ __launch_bounds__(64) void adex_kernel(
    const float* __restrict__ I,
    const float* __restrict__ v0,
    const float* __restrict__ c0,
    const int*   __restrict__ ref0,
    float*       __restrict__ out,
    int N, int T)
{
#pragma clang fp contract(off)
    const float EL       = (float)(-70.6e-3);
    const float VT       = (float)(-50.4e-3);
    const float DELTAT   = (float)(2e-3);
    const float R_DELTAT = (float)(1.0 / (double)((float)(2e-3)));  // fl(1/d)
    const float NEG_GL   = (float)(-30e-9);
    const float GLDT     = (float)(30e-9 * 2e-3);        // GL*DELTAT
    const float DT_CM    = (float)(1e-3 / 281e-12);      // DT/CM
    const float DT_TAUW  = (float)(1e-3 / 144e-3);       // DT/TAUW
    const float Af       = (float)(4e-9);
    const float Bf       = (float)(0.0805e-9);
    const int   REF_STEPS = 2;

    int n = blockIdx.x * blockDim.x + threadIdx.x;
    if (n >= N) return;

    float v  = v0[n];
    float c  = c0[n];
    int   rf = ref0[n];

    const unsigned stride_b = (unsigned)N * 4u;
    unsigned load_off  = (unsigned)n * 4u;
    unsigned store_off = load_off;

    auto ld = [&](unsigned off) -> float {
        return *(const float*)((const char*)I + off);
    };
    auto st = [&](unsigned off, float val) {
        *(float*)((char*)out + off) = val;   // plain store: retires at L2-accept
    };

    // One simulation step. Updates v, c, rf; returns v_out.
    auto step = [&](float It) -> float {
        bool  in_ref = rf > 0;
        float v_eff  = in_ref ? EL : v;

        // arg = (v_eff - VT) / DELTAT  — Newton/fma faithful division
        float x   = v_eff - VT;
        float y0  = x * R_DELTAT;
        float e   = fmaf(-DELTAT, y0, x);
        float arg = fmaf(e, R_DELTAT, y0);
        arg = fminf(arg, 15.0f);
        float exp_term = GLDT * expf(arg);

        float acc = NEG_GL * (v_eff - EL);
        acc = acc + exp_term;
        acc = acc - c;
        acc = acc + It;
        float dv = DT_CM * acc;

        float v_new = in_ref ? EL : (v_eff + dv);
        float c_new = c + DT_TAUW * ((Af * (v_eff - EL)) - c);

        bool  spike = v_new >= VT;
        float v_out = spike ? EL : v_new;

        c  = spike ? (c_new + Bf) : c_new;
        rf = spike ? REF_STEPS : (in_ref ? rf - 1 : 0);
        v  = v_out;
        return v_out;
    };

    float buf[DEPTH];

    // Prologue: preload first DEPTH values (predicated for tiny-T safety).
#pragma unroll
    for (int k = 0; k < DEPTH; ++k) {
        if (k < T) { buf[k] = ld(load_off); load_off += stride_b; }
    }

    int t = 0;
    // Main pipelined loop: consume buf[j] (loaded DEPTH steps ago), prefetch
    // step t+j+DEPTH into the same slot. All ring indices compile-time.
    for (; t + 2 * DEPTH <= T; t += DEPTH) {
#pragma unroll
        for (int j = 0; j < DEPTH; ++j) {
            float It = buf[j];
            buf[j] = ld(load_off); load_off += stride_b;
            float v_out = step(It);
            st(store_off, v_out);
            store_off += stride_b;
        }
    }

    // Epilogue: up to 2*DEPTH-1 remaining steps, unrolled + predicated.
#pragma unroll
    for (int j = 0; j < 2 * DEPTH; ++j) {
        if (t + j < T) {
            float It = buf[j % DEPTH];
            if (t + j + DEPTH < T) { buf[j % DEPTH] = ld(load_off); load_off += stride_b; }
            float v_out = step(It);
            st(store_off, v_out);
            store_off += stride_b;
        }
    }
}

extern "C" void kernel_launch(void* const* d_in, const int* in_sizes, int n_in,
                              void* d_out, int out_size, void* d_ws, size_t ws_size,
                              hipStream_t stream) {
    const float* I    = (const float*)d_in[0];
    const float* v0   = (const float*)d_in[1];
    const float* c0   = (const float*)d_in[2];
    const int*   ref0 = (const int*)d_in[3];
    float*       out  = (float*)d_out;

    int N = in_sizes[1];            // 100000
    int T = in_sizes[0] / N;        // 500

    dim3 block(64);
    dim3 grid((N + 63) / 64);       // 1563 one-wave blocks -> 6-7 waves/CU, even
    adex_kernel<<<grid, block, 0, stream>>>(I, v0, c0, ref0, out, N, T);
}